// Round 12
// baseline (357.429 us; speedup 1.0000x reference)
//
#include <hip/hip_runtime.h>

// 3x3 conv, stride 1, pad 1, NCHW/OIHW fp32. N=16, C=32, OC=32, H=W=256.
//
// R13: maximize outstanding load bytes per CU (Little's-law lever).
//  Model (R7/R10/R11/R12): achieved HBM rate == offered outstanding bytes /
//  latency, NOT a wall -- R10 served 3.0 TB/s when offered more, R12 fell
//  to 1.55 when in-flight depth shrank, copy hits 6.3 with huge depth.
//  Three moves on the verified R7/R11 base (byte-minimal 201.5 MB traffic):
//   1. ldsW ELIMINATED: weights = 18 reg-resident A-frags (72 VGPR) loaded
//      coalesced from R12's prep image. LDS 62.5->41.3 KB => 3 blocks/CU,
//      24 waves (was 16): 1.5x more load-issuing waves.
//   2. BOTH ic-halves' x loads issued at prologue: 48 float2 = 24 KB in
//      flight per wave (2x R7's burst).
//   3. free-run bar_lgkm barriers (R11: byte-safe) so co-resident blocks'
//      bursts overlap; transposed full-1KB-line epilogue (amp-proof);
//      h-pair geometry (proven 65.7 MB FETCH).
//  Verified invariants kept: XSTR=20 LDS layout, cvtpk RNE pack, A/B/D
//  lane mappings (R2/R12), prep-image path (R12 passed).

constexpr int N_  = 16;
constexpr int C_  = 32;
constexpr int OC_ = 32;
constexpr int H_  = 256;
constexpr int W_  = 256;
constexpr int HW_ = H_ * W_;

constexpr int XSTR = 20;             // ushorts per wi: 32B data (16 ic) + 8B pad
constexpr int XROW = 258 * XSTR;     // ushorts per staged row (wi = w+1)
constexpr int WGROUPS = 9 * 2 * 2 * 32;   // t9 x hf x qd x oc = 1152
constexpr int WBYTES  = WGROUPS * 16;     // 18432 B prepped weight image

typedef __attribute__((ext_vector_type(4)))  short short4v;
typedef __attribute__((ext_vector_type(8)))  short short8v;
typedef __attribute__((ext_vector_type(4)))  int   int4v;
typedef __attribute__((ext_vector_type(16))) float float16v;
typedef __attribute__((ext_vector_type(4)))  float floatx4;

// one instruction: dst.lo16 = bf16(lo), dst.hi16 = bf16(hi) (RNE)
static __device__ __forceinline__ unsigned cvtpk(float lo, float hi) {
    unsigned r;
    asm("v_cvt_pk_bf16_f32 %0, %1, %2" : "=v"(r) : "v"(lo), "v"(hi));
    return r;
}

static __device__ __forceinline__ short8v load8(const unsigned short* p) {
    // 8B-aligned: two ds_read_b64
    short4v lo = *(const short4v*)p;
    short4v hi = *(const short4v*)(p + 4);
    return __builtin_shufflevector(lo, hi, 0, 1, 2, 3, 4, 5, 6, 7);
}

// lgkm-only barrier (R11-proven): ds ops drained + wave sync; in-flight
// global loads and NT-store acks cross freely.
static __device__ __forceinline__ void bar_lgkm() {
    asm volatile("s_waitcnt lgkmcnt(0)" ::: "memory");
    __builtin_amdgcn_s_barrier();
}

// ---- prep: weight image [t9][hf][qd][oc] x 16B, bf16 (R12-verified) ----
// lane (col=oc, qd) reads group g = ((t9*2+hf)*2+qd)*32+oc as int4
// = 8 bf16 = w[oc][ic = hf*16+qd*8+j][t9], j=0..7.
__global__ void conv_w_prep(const float* __restrict__ wgt,
                            unsigned* __restrict__ wp) {
    const int g = blockIdx.x * 256 + threadIdx.x;
    if (g >= WGROUPS) return;
    const int oc  = g & 31;
    const int q   = g >> 5;          // 0..35
    const int qd  = q & 1;
    const int hf  = (q >> 1) & 1;
    const int t9  = q >> 2;
    const int icb = hf * 16 + qd * 8;
    float v[8];
    #pragma unroll
    for (int j = 0; j < 8; ++j) v[j] = wgt[(oc * 32 + icb + j) * 9 + t9];
    wp[g * 4 + 0] = cvtpk(v[0], v[1]);
    wp[g * 4 + 1] = cvtpk(v[2], v[3]);
    wp[g * 4 + 2] = cvtpk(v[4], v[5]);
    wp[g * 4 + 3] = cvtpk(v[6], v[7]);
}

template<bool USE_WS>
__global__ __launch_bounds__(512, 6) void conv3x3_mfma_kernel(
    const float* __restrict__ x,     // [N][C][H][W]
    const float* __restrict__ wgt,   // [OC][C][3][3]
    const float* __restrict__ bias,  // [OC]
    const unsigned* __restrict__ wpk,  // prepped weights (d_ws)
    float* __restrict__ out)         // [N][OC][H][W]
{
    __shared__ __align__(16) unsigned short ldsX[4 * XROW];   // 41,280 B only

    const int tid = threadIdx.x;

    // XCD-aware swizzle: 2048 blocks, 8 XCDs x 256 consecutive (n, h-pair).
    const int id = blockIdx.x;
    const int L  = (id & 7) * 256 + (id >> 3);
    const int n  = L >> 7;           // image 0..15
    const int h  = (L & 127) * 2;    // output rows h, h+1

    const int lane = tid & 63;
    const int wv   = tid >> 6;       // wave 0..7
    const int rsel = wv >> 2;        // output row select (0/1)
    const int col  = lane & 31;      // A: oc; B/D: w col
    const int qd   = lane >> 5;      // k-quad select
    const int w0a  = (wv & 3) * 64;
    const int w0b  = (wv & 3) * 64 + 32;

    // staging map: thread -> (staged row r4, w-pair wlo, ic-quad icq)
    const int r4  = tid >> 7;        // staged input row 0..3 (= h-1+r4)
    const int t7  = tid & 127;
    const int wlo = t7 & 31;         // w-pair lane
    const int icq = t7 >> 5;         // 0..3 (handles ic-pairs icq and icq+4)
    const size_t HW = (size_t)HW_;

    // ---- prologue: issue BOTH halves' x loads (48 float2 in flight) ----
    float2 A0[4], A1[4], B0[4], B1[4];   // half0
    float2 C0[4], C1[4], D0[4], D1[4];   // half1
    {
        const int hy = h - 1 + r4;
        if (hy >= 0 && hy < H_) {
            #pragma unroll
            for (int hf = 0; hf < 2; ++hf) {
                const int icg0 = hf * 16 + 2 * icq;
                const int icg1 = hf * 16 + 2 * (icq + 4);
                const float* pA0 = x + ((size_t)(n * C_ + icg0) * H_ + hy) * W_;
                const float* pA1 = pA0 + HW;
                const float* pB0 = x + ((size_t)(n * C_ + icg1) * H_ + hy) * W_;
                const float* pB1 = pB0 + HW;
                #pragma unroll
                for (int wb = 0; wb < 4; ++wb) {
                    const int w = wb * 64 + 2 * wlo;
                    if (hf == 0) {
                        A0[wb] = *(const float2*)(pA0 + w);
                        A1[wb] = *(const float2*)(pA1 + w);
                        B0[wb] = *(const float2*)(pB0 + w);
                        B1[wb] = *(const float2*)(pB1 + w);
                    } else {
                        C0[wb] = *(const float2*)(pA0 + w);
                        C1[wb] = *(const float2*)(pA1 + w);
                        D0[wb] = *(const float2*)(pB0 + w);
                        D1[wb] = *(const float2*)(pB1 + w);
                    }
                }
            }
        } else {
            #pragma unroll
            for (int wb = 0; wb < 4; ++wb) {
                A0[wb] = A1[wb] = B0[wb] = B1[wb] = make_float2(0.f, 0.f);
                C0[wb] = C1[wb] = D0[wb] = D1[wb] = make_float2(0.f, 0.f);
            }
        }
    }

    // ---- weights: 18 reg-resident A-frags, coalesced 16B loads ----
    short8v af[18];                  // index t9*2 + hf
    if (USE_WS) {
        #pragma unroll
        for (int t9 = 0; t9 < 9; ++t9) {
            #pragma unroll
            for (int hf = 0; hf < 2; ++hf) {
                const int g = ((t9 * 2 + hf) * 2 + qd) * 32 + col;
                af[t9 * 2 + hf] = __builtin_bit_cast(short8v,
                                      *(const int4v*)(wpk + (size_t)g * 4));
            }
        }
    } else {
        // fallback (no workspace): per-lane gather from OIHW
        #pragma unroll
        for (int t9 = 0; t9 < 9; ++t9) {
            #pragma unroll
            for (int hf = 0; hf < 2; ++hf) {
                const int icb = hf * 16 + qd * 8;
                unsigned u[4];
                #pragma unroll
                for (int jj = 0; jj < 4; ++jj)
                    u[jj] = cvtpk(wgt[(col * 32 + icb + 2 * jj) * 9 + t9],
                                  wgt[(col * 32 + icb + 2 * jj + 1) * 9 + t9]);
                int4v iv; iv.x = u[0]; iv.y = u[1]; iv.z = u[2]; iv.w = u[3];
                af[t9 * 2 + hf] = __builtin_bit_cast(short8v, iv);
            }
        }
    }

    // ---- acc init with bias (D row = oc mapping, verified in R2) ----
    float16v acc0, acc1;
    #pragma unroll
    for (int r = 0; r < 16; ++r) {
        const float bv = bias[(r & 3) + 8 * (r >> 2) + 4 * qd];
        acc0[r] = bv;
        acc1[r] = bv;
    }

    auto write_half = [&](float2 (&P0)[4], float2 (&P1)[4],
                          float2 (&Q0)[4], float2 (&Q1)[4]) {
        unsigned short* dst = &ldsX[r4 * XROW];
        #pragma unroll
        for (int wb = 0; wb < 4; ++wb) {
            const int w = wb * 64 + 2 * wlo;
            *(unsigned*)&dst[(w + 1) * XSTR + 2 * icq]       = cvtpk(P0[wb].x, P1[wb].x);
            *(unsigned*)&dst[(w + 2) * XSTR + 2 * icq]       = cvtpk(P0[wb].y, P1[wb].y);
            *(unsigned*)&dst[(w + 1) * XSTR + 2 * (icq + 4)] = cvtpk(Q0[wb].x, Q1[wb].x);
            *(unsigned*)&dst[(w + 2) * XSTR + 2 * (icq + 4)] = cvtpk(Q0[wb].y, Q1[wb].y);
        }
    };

    auto mfma_half = [&](int hf) {
        #pragma unroll
        for (int kh = 0; kh < 3; ++kh) {
            #pragma unroll
            for (int kw = 0; kw < 3; ++kw) {
                const int t9 = kh * 3 + kw;
                const short8v bf0 =
                    load8(&ldsX[(rsel + kh) * XROW + (w0a + col + kw) * XSTR + qd * 8]);
                const short8v bf1 =
                    load8(&ldsX[(rsel + kh) * XROW + (w0b + col + kw) * XSTR + qd * 8]);
                acc0 = __builtin_amdgcn_mfma_f32_32x32x16_bf16(af[t9 * 2 + hf], bf0, acc0, 0, 0, 0);
                acc1 = __builtin_amdgcn_mfma_f32_32x32x16_bf16(af[t9 * 2 + hf], bf1, acc1, 0, 0, 0);
            }
        }
    };

    // ---- pack + write half0; halo zeros (persist across both halves) ----
    write_half(A0, A1, B0, B1);
    if (tid < 32) {
        const int r  = tid >> 3;                 // staged row 0..3
        const int q  = tid & 7;
        const int wi = (q & 4) ? 257 : 0;
        const int c  = q & 3;
        *(unsigned long long*)&ldsX[r * XROW + wi * XSTR + c * 4] = 0ull;
    }
    bar_lgkm();                      // X0 staged

    mfma_half(0);
    bar_lgkm();                      // MFMA0 ds reads done

    write_half(C0, C1, D0, D1);      // half1 (loads landed long ago)
    bar_lgkm();                      // X1 staged
    mfma_half(1);

    // ---- epilogue: LDS transpose -> full 1KB-per-instr NT row stores ----
    bar_lgkm();                      // all frag reads of ldsX done
    float* scr = (float*)&ldsX[0];   // 32 KB scratch: [32 oc][256 w]
    #pragma unroll
    for (int rr = 0; rr < 2; ++rr) {
        if (rsel == rr) {            // wave-uniform branch
            #pragma unroll
            for (int r = 0; r < 16; ++r) {
                const int oc = (r & 3) + 8 * (r >> 2) + 4 * qd;
                scr[oc * 256 + w0a + col] = acc0[r];
                scr[oc * 256 + w0b + col] = acc1[r];
            }
        }
        bar_lgkm();                  // scratch visible
        float* outp = out + (size_t)n * OC_ * HW + (size_t)(h + rr) * W_;
        #pragma unroll
        for (int k = 0; k < 4; ++k) {
            const int oc = wv * 4 + k;
            const floatx4 v = *(const floatx4*)&scr[oc * 256 + lane * 4];
            floatx4* dp = (floatx4*)(outp + (size_t)oc * HW + lane * 4);
            __builtin_nontemporal_store(v, dp);
        }
        if (rr == 0) bar_lgkm();     // row0 scr reads done before row1 dump
    }
}

extern "C" void kernel_launch(void* const* d_in, const int* in_sizes, int n_in,
                              void* d_out, int out_size, void* d_ws, size_t ws_size,
                              hipStream_t stream) {
    const float* x    = (const float*)d_in[0];
    const float* wgt  = (const float*)d_in[1];
    const float* bias = (const float*)d_in[2];
    float* out        = (float*)d_out;

    dim3 grid(N_ * H_ / 2);   // 2048 blocks: one per (n, h-pair)
    dim3 block(512);

    if (d_ws != nullptr && ws_size >= (size_t)WBYTES) {
        unsigned* wp = (unsigned*)d_ws;
        conv_w_prep<<<dim3(5), dim3(256), 0, stream>>>(wgt, wp);
        conv3x3_mfma_kernel<true><<<grid, block, 0, stream>>>(x, wgt, bias, wp, out);
    } else {
        conv3x3_mfma_kernel<false><<<grid, block, 0, stream>>>(x, wgt, bias, nullptr, out);
    }
}